// Round 2
// baseline (133.078 us; speedup 1.0000x reference)
//
#include <hip/hip_runtime.h>
#include <hip/hip_bf16.h>
#include <stdint.h>

// SVM RBF layer: out[j] = b + sum_i a[i]*Y[i]*exp(-g*max(||x_i||^2+||z_j||^2-2*x_i.z_j, 0))
// N=8192 support vectors, M=4096 query points, d=512.
#define GAMMA_F 0.001953125f

static constexpr int N_SV = 8192;
static constexpr int M_Q  = 4096;
static constexpr int DIM  = 512;

typedef __bf16 bf16x8 __attribute__((ext_vector_type(8)));
typedef float  f32x4  __attribute__((ext_vector_type(4)));

#define GLB const __attribute__((address_space(1))) void
#define LDS __attribute__((address_space(3))) void

// ---------------- prep: fp32 -> bf16 + row norms + weights -------------------
// One wave per row. r < N_SV: X row; else: Z row.
__global__ __launch_bounds__(64) void svm_prep(
    const float* __restrict__ Z, const float* __restrict__ X,
    const float* __restrict__ Y, const float* __restrict__ a,
    __bf16* __restrict__ Xb, __bf16* __restrict__ Zb,
    float* __restrict__ xn, float* __restrict__ zn, float* __restrict__ w)
{
    const int r = blockIdx.x;
    const int t = threadIdx.x;   // 0..63, each handles 8 floats
    const float* src;
    __bf16* dst;
    if (r < N_SV) { src = X + (size_t)r * DIM; dst = Xb + (size_t)r * DIM; }
    else          { src = Z + (size_t)(r - N_SV) * DIM; dst = Zb + (size_t)(r - N_SV) * DIM; }

    float4 v0 = ((const float4*)src)[t * 2];
    float4 v1 = ((const float4*)src)[t * 2 + 1];

    float s = v0.x*v0.x + v0.y*v0.y + v0.z*v0.z + v0.w*v0.w
            + v1.x*v1.x + v1.y*v1.y + v1.z*v1.z + v1.w*v1.w;

    __bf16 h[8];
    h[0] = (__bf16)v0.x; h[1] = (__bf16)v0.y; h[2] = (__bf16)v0.z; h[3] = (__bf16)v0.w;
    h[4] = (__bf16)v1.x; h[5] = (__bf16)v1.y; h[6] = (__bf16)v1.z; h[7] = (__bf16)v1.w;
    uint4 bits;
    __builtin_memcpy(&bits, h, 16);
    ((uint4*)dst)[t] = bits;

    #pragma unroll
    for (int o = 32; o > 0; o >>= 1) s += __shfl_xor(s, o);

    if (t == 0) {
        if (r < N_SV) { xn[r] = s; w[r] = a[r] * Y[r]; }
        else          { zn[r - N_SV] = s; }
    }
}

// ---------------- init: out[j] = b ------------------------------------------
__global__ __launch_bounds__(256) void svm_init(float* __restrict__ out,
                                                const float* __restrict__ b)
{
    int j = blockIdx.x * 256 + threadIdx.x;
    if (j < M_Q) out[j] = b[0];
}

// ---------------- main fused tile kernel ------------------------------------
// 128x128 output tile (i x j), BK=32, 4 waves in 2x2, each wave 64x64 via
// 4x4 fragments of v_mfma_f32_16x16x32_bf16. Epilogue applies RBF + weight
// and reduces over the i-dimension, atomicAdd into out[j].
__global__ __launch_bounds__(256) void svm_main(
    const __bf16* __restrict__ Xb, const __bf16* __restrict__ Zb,
    const float* __restrict__ xn, const float* __restrict__ zn,
    const float* __restrict__ w, float* __restrict__ out)
{
    __shared__ __bf16 As[128 * 32];   // 8 KB: rows = i within tile, cols = k
    __shared__ __bf16 Bs[128 * 32];   // 8 KB: rows = j within tile, cols = k

    const int tid  = threadIdx.x;      // 0..255
    const int lane = tid & 63;
    const int wid  = tid >> 6;         // 0..3
    const int wr   = wid >> 1;         // wave row (i)  in {0,1}
    const int wc   = wid & 1;          // wave col (j)  in {0,1}

    const int bi = blockIdx.y;         // i tile: 0..63
    const int bj = blockIdx.x;         // j tile: 0..31
    const int iBase = bi * 128;
    const int jBase = bj * 128;

    f32x4 acc[4][4];
    #pragma unroll
    for (int m = 0; m < 4; ++m)
        #pragma unroll
        for (int n = 0; n < 4; ++n)
            acc[m][n] = (f32x4)(0.0f);

    // staging: flat byte f = q*4096 + tid*16 -> row = f/64, byte-in-row = f%64
    const int srow = tid >> 2;            // 0..63 (q adds 64)
    const int scb  = (tid & 3) * 16;      // byte offset within 64B row
    const int sce  = scb >> 1;            // element offset within row

    const int lrow = lane & 15;
    const int lk   = (lane >> 4) * 8;     // k-element offset of this lane's fragment

    for (int k0 = 0; k0 < DIM; k0 += 32) {
        #pragma unroll
        for (int q = 0; q < 2; ++q) {
            const int row = q * 64 + srow;
            const __bf16* sa = Xb + (size_t)(iBase + row) * DIM + k0 + sce;
            __builtin_amdgcn_global_load_lds((GLB*)sa,
                (LDS*)((char*)As + q * 4096 + tid * 16), 16, 0, 0);
            const __bf16* sb = Zb + (size_t)(jBase + row) * DIM + k0 + sce;
            __builtin_amdgcn_global_load_lds((GLB*)sb,
                (LDS*)((char*)Bs + q * 4096 + tid * 16), 16, 0, 0);
        }
        __syncthreads();   // compiler emits vmcnt(0) drain before barrier

        bf16x8 af[4], bfr[4];
        #pragma unroll
        for (int m = 0; m < 4; ++m)
            af[m] = *(const bf16x8*)(As + (wr * 64 + m * 16 + lrow) * 32 + lk);
        #pragma unroll
        for (int n = 0; n < 4; ++n)
            bfr[n] = *(const bf16x8*)(Bs + (wc * 64 + n * 16 + lrow) * 32 + lk);

        #pragma unroll
        for (int m = 0; m < 4; ++m)
            #pragma unroll
            for (int n = 0; n < 4; ++n)
                acc[m][n] = __builtin_amdgcn_mfma_f32_16x16x32_bf16(
                    af[m], bfr[n], acc[m][n], 0, 0, 0);

        __syncthreads();   // protect LDS before next stage overwrites
    }

    // ---- fused RBF epilogue ----
    // C fragment (16x16x32): col = lane&15, row = (lane>>4)*4 + reg  [m89]
    const int rg   = lane >> 4;
    const int lcol = lane & 15;

    float wv[16], xv[16];
    #pragma unroll
    for (int m = 0; m < 4; ++m)
        #pragma unroll
        for (int r = 0; r < 4; ++r) {
            const int i = iBase + wr * 64 + m * 16 + rg * 4 + r;
            wv[m * 4 + r] = w[i];
            xv[m * 4 + r] = xn[i];
        }

    #pragma unroll
    for (int n = 0; n < 4; ++n) {
        const int j = jBase + wc * 64 + n * 16 + lcol;
        const float znj = zn[j];
        float cs = 0.0f;
        #pragma unroll
        for (int m = 0; m < 4; ++m)
            #pragma unroll
            for (int r = 0; r < 4; ++r) {
                float d = xv[m * 4 + r] + znj - 2.0f * acc[m][n][r];
                d = fmaxf(d, 0.0f);
                cs += wv[m * 4 + r] * __expf(-GAMMA_F * d);
            }
        // reduce across the 4 row-groups (lanes 16 apart hold other i-rows)
        cs += __shfl_xor(cs, 16);
        cs += __shfl_xor(cs, 32);
        if (lane < 16) atomicAdd(out + j, cs);
    }
}

// ---------------- launch -----------------------------------------------------
extern "C" void kernel_launch(void* const* d_in, const int* in_sizes, int n_in,
                              void* d_out, int out_size, void* d_ws, size_t ws_size,
                              hipStream_t stream)
{
    const float* Z = (const float*)d_in[0];   // inputs [4096, 512]
    const float* X = (const float*)d_in[1];   // X      [8192, 512]
    const float* Y = (const float*)d_in[2];   // Y      [8192, 1]
    const float* a = (const float*)d_in[3];   // a      [8192, 1]
    const float* b = (const float*)d_in[4];   // b      [1, 1]
    float* out = (float*)d_out;               // [4096, 1]

    char* ws = (char*)d_ws;
    __bf16* Xb = (__bf16*)ws;                                   // 8 MB
    __bf16* Zb = (__bf16*)(ws + 8ull * 1024 * 1024);            // 4 MB
    float*  xn = (float*)(ws + 12ull * 1024 * 1024);            // 32 KB
    float*  zn = xn + N_SV;                                     // 16 KB
    float*  w  = zn + M_Q;                                      // 32 KB

    svm_prep<<<N_SV + M_Q, 64, 0, stream>>>(Z, X, Y, a, Xb, Zb, xn, zn, w);
    svm_init<<<(M_Q + 255) / 256, 256, 0, stream>>>(out, b);
    svm_main<<<dim3(M_Q / 128, N_SV / 128), 256, 0, stream>>>(Xb, Zb, xn, zn, w, out);
}